// Round 8
// baseline (457.431 us; speedup 1.0000x reference)
//
#include <hip/hip_runtime.h>

// MultiHeadAttention fwd: out = (ctx @ Wo, attn_weights)
// fp16 MFMA (16x16x32), fp32 accumulate.
// R8: SINGLE-PASS attn. Unnormalized p=exp(logit) kept in LDS (Pw, 128KB,
//     wave-private 16x1024 fp16 rows). Phase 1: QK^T once + exp -> Pw + ssum.
//     Phase 2: V-tiles, attnW = fp16(p)*inv (dwordx4), PV with raw p,
//     ctx scaled by per-row inv at the end. 148KB LDS, 1 block/CU.
// d_out = [output fp32 16*1024*512][attn_weights fp32 16*8*1024*1024]

typedef _Float16 f16;
typedef _Float16 f16x8 __attribute__((ext_vector_type(8)));
typedef _Float16 f16x4 __attribute__((ext_vector_type(4)));
typedef float f32x4 __attribute__((ext_vector_type(4)));

#define DEVINL __device__ __forceinline__

static constexpr int BATCH = 16, SEQ = 1024, DM = 512, NH = 8, DH = 64;

DEVINL void async16(void* lds, const void* g) {
  __builtin_amdgcn_global_load_lds(
      (const __attribute__((address_space(1))) unsigned int*)g,
      (__attribute__((address_space(3))) unsigned int*)lds, 16, 0, 0);
}

// ---------------- weight fp32[k][n] -> fp16 WT[w][n][k] ----------------
__global__ __launch_bounds__(256) void prep_wt_k(
    const float* __restrict__ Wq, const float* __restrict__ Wk,
    const float* __restrict__ Wv, const float* __restrict__ Wo,
    f16* __restrict__ WT) {
  __shared__ float t[32][33];
  const int w = blockIdx.z;
  const float* src = (w == 0) ? Wq : (w == 1) ? Wk : (w == 2) ? Wv : Wo;
  const int k0 = blockIdx.y * 32, n0 = blockIdx.x * 32;
  const int r0 = threadIdx.x >> 5, c = threadIdx.x & 31;
#pragma unroll
  for (int i = 0; i < 4; ++i)
    t[i * 8 + r0][c] = src[(size_t)(k0 + i * 8 + r0) * DM + n0 + c];
  __syncthreads();
  f16* dst = WT + (size_t)w * DM * DM;
#pragma unroll
  for (int i = 0; i < 4; ++i)
    dst[(size_t)(n0 + i * 8 + r0) * DM + k0 + c] = (f16)t[c][i * 8 + r0];
}

// ---------------- 128x128x(K=512) MFMA GEMM body, double-buffered ----------------
template <int MODE>
DEVINL void gemm_body(const float* __restrict__ A32, const f16* __restrict__ A16,
                      const f16* __restrict__ WTn, f16* __restrict__ O16,
                      float* __restrict__ O32, int m0, int n0, bool vt) {
  __shared__ __align__(16) f16 As[2][128 * 32];
  __shared__ __align__(16) f16 Bs[2][128 * 32];
  const int tid = threadIdx.x;
  const int lane = tid & 63, wave = tid >> 6;
  const int wr = wave >> 1, wc = wave & 1;
  const int lrow = lane & 15, lkg = lane >> 4;
  f32x4 acc[4][4] = {};

  f32x4 ar[4];

  auto stageB = [&](int kt, int buf) {
#pragma unroll
    for (int it = 0; it < 2; ++it) {
      const int o = (it * 256 + tid) * 16;
      const int n = o >> 6, kb = o & 63;
      async16((char*)&Bs[buf][0] + (it * 256 + wave * 64) * 16,
              (const char*)WTn + ((size_t)(n0 + n) * DM + kt * 32) * 2 + kb);
    }
  };
  auto stageA_async = [&](int kt, int buf) {
#pragma unroll
    for (int it = 0; it < 2; ++it) {
      const int o = (it * 256 + tid) * 16;
      const int row = o >> 6, kb = o & 63;
      async16((char*)&As[buf][0] + (it * 256 + wave * 64) * 16,
              (const char*)A16 + ((size_t)(m0 + row) * DM + kt * 32) * 2 + kb);
    }
  };
  auto loadA = [&](int kt) {
#pragma unroll
    for (int c = 0; c < 4; ++c) {
      const int idx = c * 256 + tid;
      const int row = idx >> 3, sub = idx & 7;
      ar[c] = *(const f32x4*)(A32 + (size_t)(m0 + row) * DM + kt * 32 + sub * 4);
    }
  };
  auto writeA = [&](int buf) {
#pragma unroll
    for (int c = 0; c < 4; ++c) {
      const int idx = c * 256 + tid;
      const int row = idx >> 3, sub = idx & 7;
      f16x4 t;
      t[0] = (f16)ar[c][0]; t[1] = (f16)ar[c][1];
      t[2] = (f16)ar[c][2]; t[3] = (f16)ar[c][3];
      *(f16x4*)&As[buf][row * 32 + sub * 4] = t;
    }
  };

  stageB(0, 0);
  if (MODE == 0) {
    loadA(0);
    writeA(0);
  } else {
    stageA_async(0, 0);
  }
  __syncthreads();

  for (int kt = 0; kt < DM / 32; ++kt) {
    const int cur = kt & 1;
    if (kt < DM / 32 - 1) {
      stageB(kt + 1, cur ^ 1);
      if (MODE == 0) loadA(kt + 1);
      else stageA_async(kt + 1, cur ^ 1);
    }
    f16x8 af[4], bf[4];
#pragma unroll
    for (int i = 0; i < 4; ++i)
      af[i] = *(const f16x8*)&As[cur][(wr * 64 + i * 16 + lrow) * 32 + lkg * 8];
#pragma unroll
    for (int j = 0; j < 4; ++j)
      bf[j] = *(const f16x8*)&Bs[cur][(wc * 64 + j * 16 + lrow) * 32 + lkg * 8];
#pragma unroll
    for (int i = 0; i < 4; ++i)
#pragma unroll
      for (int j = 0; j < 4; ++j)
        acc[i][j] = __builtin_amdgcn_mfma_f32_16x16x32_f16(af[i], bf[j], acc[i][j], 0, 0, 0);
    if (MODE == 0 && kt < DM / 32 - 1) writeA(cur ^ 1);
    __syncthreads();
  }

#pragma unroll
  for (int i = 0; i < 4; ++i) {
#pragma unroll
    for (int j = 0; j < 4; ++j) {
#pragma unroll
      for (int r = 0; r < 4; ++r) {
        const int m = m0 + wr * 64 + i * 16 + lkg * 4 + r;
        const int g = n0 + wc * 64 + j * 16 + lrow;
        if (MODE == 0) {
          const int b = m >> 10, s = m & 1023, hh = g >> 6, d = g & 63;
          if (vt)
            O16[(((size_t)b * NH + hh) * DH + d) * SEQ + s] = (f16)acc[i][j][r];
          else
            O16[(((size_t)b * NH + hh) * SEQ + s) * DH + d] = (f16)acc[i][j][r];
        } else {
          O32[(size_t)m * DM + g] = acc[i][j][r];
        }
      }
    }
  }
}

__global__ __launch_bounds__(256, 2) void proj_k(
    const float* __restrict__ q, const float* __restrict__ k, const float* __restrict__ v,
    const f16* __restrict__ WT, f16* __restrict__ Qh, f16* __restrict__ Kh,
    f16* __restrict__ Vh) {
  const int bid = blockIdx.x;
  const int wid = (bid & 7) * 192 + (bid >> 3);
  const int n_blk = wid & 3, m_blk = (wid >> 2) & 127, z = wid >> 9;
  const float* A = (z == 0) ? q : (z == 1) ? k : v;
  const f16* W = WT + (size_t)z * DM * DM;
  f16* O = (z == 0) ? Qh : (z == 1) ? Kh : Vh;
  gemm_body<0>(A, nullptr, W, O, nullptr, m_blk * 128, n_blk * 128, z == 2);
}

__global__ __launch_bounds__(256, 2) void outp_k(const f16* __restrict__ ctx,
                                                 const f16* __restrict__ WoT,
                                                 float* __restrict__ out0) {
  const int bid = blockIdx.x;
  const int wid = (bid & 7) * 64 + (bid >> 3);
  const int n_blk = wid & 3, m_blk = wid >> 2;
  gemm_body<1>(nullptr, ctx, WoT, nullptr, out0, m_blk * 128, n_blk * 128, false);
}

// ---------------- attention (single-pass) ----------------
// Swapped QK^T: acc = logits[key][q], q = lane&15 (lq), keys = 16j + 4g + r.
// Pw[wave]: 16 rows (lq) x 1024 keys fp16, row stride 2048B; 16B slot s holds
// keys [8s, 8s+8); stored at slot (s ^ (lq&7)) for bank spread.
// Phase 1: QK^T once, p=exp (unnormalized) -> Pw, ssum from rounded p.
// Phase 2: V-tiles; attnW = (float)p * inv (f32x4 stores); PV with raw p;
// ctx scaled by per-row inv at the end.
__global__ __launch_bounds__(256, 1) void attn_k(
    const f16* __restrict__ Qh, const f16* __restrict__ Kh, const f16* __restrict__ VTh,
    const float* __restrict__ mask, float* __restrict__ attnW, f16* __restrict__ ctx) {
  __shared__ __align__(16) f16 st[2][64 * 64];      // 16 KB: K (ph1) / V (ph2) staging
  __shared__ __align__(16) f16 Pw[4][16 * 1024];    // 128 KB
  __shared__ __align__(16) float Ms[SEQ];           // 4 KB
  const int tid = threadIdx.x;
  const int lane = tid & 63, wave = tid >> 6;
  const int lq = lane & 15, g = lane >> 4;
  const int bid = blockIdx.x;
  const int wid = (bid & 7) * 256 + (bid >> 3);
  const int qt = wid & 15, h = (wid >> 4) & 7, b = wid >> 7;
  const size_t bh = (size_t)b * NH + h;
  const char* Kbase = (const char*)(Kh + bh * SEQ * DH);
  const char* VTbase = (const char*)(VTh + bh * (size_t)DH * SEQ);
  const int q0 = qt * 64 + wave * 16;

  auto stageK = [&](int kt, int buf) {
    const char* KtileB = Kbase + (size_t)kt * 64 * DH * 2;
#pragma unroll
    for (int it = 0; it < 2; ++it) {
      const int o = (it * 256 + tid) * 16;
      const int key = o >> 7, slot = (o >> 4) & 7;
      async16((char*)&st[buf][0] + (it * 256 + wave * 64) * 16,
              KtileB + key * 128 + ((slot ^ (key & 7)) << 4));
    }
  };
  auto stageV = [&](int kt, int buf) {
    const char* VtileB = VTbase + (size_t)kt * 64 * 2;
#pragma unroll
    for (int it = 0; it < 2; ++it) {
      const int o = (it * 256 + tid) * 16;
      const int d = o >> 7, slot = (o >> 4) & 7;
      async16((char*)&st[buf][0] + (it * 256 + wave * 64) * 16,
              VtileB + (size_t)d * (SEQ * 2) + ((slot ^ (d & 7)) << 4));
    }
  };

  // bias preload (before first barrier)
  {
    f32x4 mv = *(const f32x4*)(mask + (size_t)b * SEQ + tid * 4);
    f32x4 bv;
    bv[0] = (1.0f - mv[0]) * (-1e9f);
    bv[1] = (1.0f - mv[1]) * (-1e9f);
    bv[2] = (1.0f - mv[2]) * (-1e9f);
    bv[3] = (1.0f - mv[3]) * (-1e9f);
    *(f32x4*)&Ms[tid * 4] = bv;
  }

  // Q fragments (B-operand; row q = lq, k = g*8..)
  f16x8 aQ0, aQ1;
  {
    const f16* qp = Qh + (bh * SEQ + q0 + lq) * DH + g * 8;
    aQ0 = *(const f16x8*)qp;
    aQ1 = *(const f16x8*)(qp + 32);
  }

  // ---- phase 1: QK^T once, p -> Pw, ssum ----
  stageK(0, 0);
  __syncthreads();
  float ssum = 0.0f;
  for (int kt = 0; kt < 16; ++kt) {
    const int cur = kt & 1;
    if (kt < 15) stageK(kt + 1, cur ^ 1);
    f32x4 lg[4] = {};
#pragma unroll
    for (int j = 0; j < 4; ++j) {
      const int krow = j * 16 + lq;
      f16x8 a0 = *(const f16x8*)((const char*)&st[cur][0] + krow * 128 + ((g ^ (krow & 7)) << 4));
      f16x8 a1 = *(const f16x8*)((const char*)&st[cur][0] + krow * 128 + (((4 + g) ^ (krow & 7)) << 4));
      lg[j] = __builtin_amdgcn_mfma_f32_16x16x32_f16(a0, aQ0, lg[j], 0, 0, 0);
      lg[j] = __builtin_amdgcn_mfma_f32_16x16x32_f16(a1, aQ1, lg[j], 0, 0, 0);
    }
#pragma unroll
    for (int j = 0; j < 4; ++j) {
      f32x4 bias = *(const f32x4*)&Ms[kt * 64 + j * 16 + g * 4];
      f16x4 pw;
#pragma unroll
      for (int r = 0; r < 4; ++r) {
        const float p = __expf(lg[j][r] * 0.125f + bias[r]);
        pw[r] = (f16)p;
        ssum += (float)pw[r];  // sum the rounded values for consistency
      }
      const int s = kt * 8 + j * 2 + (g >> 1);
      *(f16x4*)((char*)&Pw[wave][0] + lq * 2048 + ((s ^ (lq & 7)) << 4) + (g & 1) * 8) = pw;
    }
    __syncthreads();
  }

  // per-row denominators: reduce across g-groups (row = lq)
  ssum += __shfl_xor(ssum, 16);
  ssum += __shfl_xor(ssum, 32);
  const float inv = 1.0f / ssum;

  // ---- phase 2: V-tiles, attnW stores, PV ----
  f32x4 ctxacc[4] = {};
  float* awBase = attnW + (bh * SEQ + q0) * SEQ;

  stageV(0, 0);
  __syncthreads();
  for (int kt = 0; kt < 16; ++kt) {
    const int cur = kt & 1;
    if (kt < 15) stageV(kt + 1, cur ^ 1);
    // attnW flush: w = p * inv (row lq, keys kt*64 + j*16 + g*4 .. +4)
#pragma unroll
    for (int j = 0; j < 4; ++j) {
      const int s = kt * 8 + j * 2 + (g >> 1);
      f16x4 pw = *(const f16x4*)((const char*)&Pw[wave][0] + lq * 2048 +
                                 ((s ^ (lq & 7)) << 4) + (g & 1) * 8);
      f32x4 w;
      w[0] = (float)pw[0] * inv; w[1] = (float)pw[1] * inv;
      w[2] = (float)pw[2] * inv; w[3] = (float)pw[3] * inv;
      *(f32x4*)(awBase + (size_t)lq * SEQ + kt * 64 + j * 16 + g * 4) = w;
    }
    // PV: ctx[q][d] += p[q][k] V[k][d]  (unnormalized p)
#pragma unroll
    for (int kk = 0; kk < 2; ++kk) {
      const int s = kt * 8 + kk * 4 + g;
      f16x8 aP = *(const f16x8*)((const char*)&Pw[wave][0] + lq * 2048 + ((s ^ (lq & 7)) << 4));
#pragma unroll
      for (int j2 = 0; j2 < 4; ++j2) {
        const int drow = j2 * 16 + lq;
        f16x8 bV = *(const f16x8*)((const char*)&st[cur][0] + drow * 128 +
                                   (((4 * kk + g) ^ (drow & 7)) << 4));
        ctxacc[j2] = __builtin_amdgcn_mfma_f32_16x16x32_f16(aP, bV, ctxacc[j2], 0, 0, 0);
      }
    }
    __syncthreads();
  }

  // redistribute inv to C-layout rows: lane (lq,g) holds ctx rows g*4+r
  float invR[4];
#pragma unroll
  for (int r = 0; r < 4; ++r) invR[r] = __shfl(inv, g * 4 + r, 64);

  // ctx layout [b][s][h][d]: row = g*4+r (q-local), col = lq (d-local)
#pragma unroll
  for (int j2 = 0; j2 < 4; ++j2)
#pragma unroll
    for (int r = 0; r < 4; ++r) {
      const int s = q0 + g * 4 + r;
      const int d = j2 * 16 + lq;
      ctx[(((size_t)b * SEQ + s) * NH + h) * DH + d] = (f16)(ctxacc[j2][r] * invR[r]);
    }
}

extern "C" void kernel_launch(void* const* d_in, const int* in_sizes, int n_in,
                              void* d_out, int out_size, void* d_ws, size_t ws_size,
                              hipStream_t stream) {
  const float* v = (const float*)d_in[0];
  const float* k = (const float*)d_in[1];
  const float* q = (const float*)d_in[2];
  const float* mask = (const float*)d_in[3];
  const float* Wq = (const float*)d_in[4];
  const float* Wk = (const float*)d_in[5];
  const float* Wv = (const float*)d_in[6];
  const float* Wo = (const float*)d_in[7];

  float* out0 = (float*)d_out;
  float* attnW = out0 + (size_t)BATCH * SEQ * DM;

  char* ws = (char*)d_ws;
  f16* WT = (f16*)ws;
  f16* Qh = (f16*)(ws + (size_t)4 * DM * DM * 2);
  f16* Kh = Qh + (size_t)BATCH * NH * SEQ * DH;
  f16* VTh = Kh + (size_t)BATCH * NH * SEQ * DH;  // [b][h][d][s]
  f16* ctx = VTh + (size_t)BATCH * NH * SEQ * DH;

  prep_wt_k<<<dim3(16, 16, 4), 256, 0, stream>>>(Wq, Wk, Wv, Wo, WT);
  proj_k<<<dim3(1536), 256, 0, stream>>>(q, k, v, WT, Qh, Kh, VTh);
  attn_k<<<dim3(2048), 256, 0, stream>>>(Qh, Kh, VTh, mask, attnW, ctx);
  outp_k<<<dim3(512), 256, 0, stream>>>(ctx, WT + (size_t)3 * DM * DM, out0);
}

// Round 9
// 327.848 us; speedup vs baseline: 1.3953x; 1.3953x over previous
//
#include <hip/hip_runtime.h>

// MultiHeadAttention fwd: out = (ctx @ Wo, attn_weights)
// fp16 MFMA (16x16x32), fp32 accumulate.
// R9: attn blocks own 256 q-rows (4 subtiles x 64): K/V staged ONCE per
//     4 q-subtiles -> staging traffic 1.5GB -> 384MB. K-frags hoisted to
//     regs and reused across subtiles. Grid 512 (2 blocks/CU), LDS 68KB.
// d_out = [output fp32 16*1024*512][attn_weights fp32 16*8*1024*1024]

typedef _Float16 f16;
typedef _Float16 f16x8 __attribute__((ext_vector_type(8)));
typedef _Float16 f16x4 __attribute__((ext_vector_type(4)));
typedef float f32x4 __attribute__((ext_vector_type(4)));

#define DEVINL __device__ __forceinline__

static constexpr int BATCH = 16, SEQ = 1024, DM = 512, NH = 8, DH = 64;

DEVINL void async16(void* lds, const void* g) {
  __builtin_amdgcn_global_load_lds(
      (const __attribute__((address_space(1))) unsigned int*)g,
      (__attribute__((address_space(3))) unsigned int*)lds, 16, 0, 0);
}

// ---------------- weight fp32[k][n] -> fp16 WT[w][n][k] ----------------
__global__ __launch_bounds__(256) void prep_wt_k(
    const float* __restrict__ Wq, const float* __restrict__ Wk,
    const float* __restrict__ Wv, const float* __restrict__ Wo,
    f16* __restrict__ WT) {
  __shared__ float t[32][33];
  const int w = blockIdx.z;
  const float* src = (w == 0) ? Wq : (w == 1) ? Wk : (w == 2) ? Wv : Wo;
  const int k0 = blockIdx.y * 32, n0 = blockIdx.x * 32;
  const int r0 = threadIdx.x >> 5, c = threadIdx.x & 31;
#pragma unroll
  for (int i = 0; i < 4; ++i)
    t[i * 8 + r0][c] = src[(size_t)(k0 + i * 8 + r0) * DM + n0 + c];
  __syncthreads();
  f16* dst = WT + (size_t)w * DM * DM;
#pragma unroll
  for (int i = 0; i < 4; ++i)
    dst[(size_t)(n0 + i * 8 + r0) * DM + k0 + c] = (f16)t[c][i * 8 + r0];
}

// ---------------- 128x128x(K=512) MFMA GEMM body, double-buffered ----------------
template <int MODE>
DEVINL void gemm_body(const float* __restrict__ A32, const f16* __restrict__ A16,
                      const f16* __restrict__ WTn, f16* __restrict__ O16,
                      float* __restrict__ O32, int m0, int n0, bool vt) {
  __shared__ __align__(16) f16 As[2][128 * 32];
  __shared__ __align__(16) f16 Bs[2][128 * 32];
  const int tid = threadIdx.x;
  const int lane = tid & 63, wave = tid >> 6;
  const int wr = wave >> 1, wc = wave & 1;
  const int lrow = lane & 15, lkg = lane >> 4;
  f32x4 acc[4][4] = {};

  f32x4 ar[4];

  auto stageB = [&](int kt, int buf) {
#pragma unroll
    for (int it = 0; it < 2; ++it) {
      const int o = (it * 256 + tid) * 16;
      const int n = o >> 6, kb = o & 63;
      async16((char*)&Bs[buf][0] + (it * 256 + wave * 64) * 16,
              (const char*)WTn + ((size_t)(n0 + n) * DM + kt * 32) * 2 + kb);
    }
  };
  auto stageA_async = [&](int kt, int buf) {
#pragma unroll
    for (int it = 0; it < 2; ++it) {
      const int o = (it * 256 + tid) * 16;
      const int row = o >> 6, kb = o & 63;
      async16((char*)&As[buf][0] + (it * 256 + wave * 64) * 16,
              (const char*)A16 + ((size_t)(m0 + row) * DM + kt * 32) * 2 + kb);
    }
  };
  auto loadA = [&](int kt) {
#pragma unroll
    for (int c = 0; c < 4; ++c) {
      const int idx = c * 256 + tid;
      const int row = idx >> 3, sub = idx & 7;
      ar[c] = *(const f32x4*)(A32 + (size_t)(m0 + row) * DM + kt * 32 + sub * 4);
    }
  };
  auto writeA = [&](int buf) {
#pragma unroll
    for (int c = 0; c < 4; ++c) {
      const int idx = c * 256 + tid;
      const int row = idx >> 3, sub = idx & 7;
      f16x4 t;
      t[0] = (f16)ar[c][0]; t[1] = (f16)ar[c][1];
      t[2] = (f16)ar[c][2]; t[3] = (f16)ar[c][3];
      *(f16x4*)&As[buf][row * 32 + sub * 4] = t;
    }
  };

  stageB(0, 0);
  if (MODE == 0) {
    loadA(0);
    writeA(0);
  } else {
    stageA_async(0, 0);
  }
  __syncthreads();

  for (int kt = 0; kt < DM / 32; ++kt) {
    const int cur = kt & 1;
    if (kt < DM / 32 - 1) {
      stageB(kt + 1, cur ^ 1);
      if (MODE == 0) loadA(kt + 1);
      else stageA_async(kt + 1, cur ^ 1);
    }
    f16x8 af[4], bf[4];
#pragma unroll
    for (int i = 0; i < 4; ++i)
      af[i] = *(const f16x8*)&As[cur][(wr * 64 + i * 16 + lrow) * 32 + lkg * 8];
#pragma unroll
    for (int j = 0; j < 4; ++j)
      bf[j] = *(const f16x8*)&Bs[cur][(wc * 64 + j * 16 + lrow) * 32 + lkg * 8];
#pragma unroll
    for (int i = 0; i < 4; ++i)
#pragma unroll
      for (int j = 0; j < 4; ++j)
        acc[i][j] = __builtin_amdgcn_mfma_f32_16x16x32_f16(af[i], bf[j], acc[i][j], 0, 0, 0);
    if (MODE == 0 && kt < DM / 32 - 1) writeA(cur ^ 1);
    __syncthreads();
  }

#pragma unroll
  for (int i = 0; i < 4; ++i) {
#pragma unroll
    for (int j = 0; j < 4; ++j) {
#pragma unroll
      for (int r = 0; r < 4; ++r) {
        const int m = m0 + wr * 64 + i * 16 + lkg * 4 + r;
        const int g = n0 + wc * 64 + j * 16 + lrow;
        if (MODE == 0) {
          const int b = m >> 10, s = m & 1023, hh = g >> 6, d = g & 63;
          if (vt)
            O16[(((size_t)b * NH + hh) * DH + d) * SEQ + s] = (f16)acc[i][j][r];
          else
            O16[(((size_t)b * NH + hh) * SEQ + s) * DH + d] = (f16)acc[i][j][r];
        } else {
          O32[(size_t)m * DM + g] = acc[i][j][r];
        }
      }
    }
  }
}

__global__ __launch_bounds__(256, 2) void proj_k(
    const float* __restrict__ q, const float* __restrict__ k, const float* __restrict__ v,
    const f16* __restrict__ WT, f16* __restrict__ Qh, f16* __restrict__ Kh,
    f16* __restrict__ Vh) {
  const int bid = blockIdx.x;
  const int wid = (bid & 7) * 192 + (bid >> 3);
  const int n_blk = wid & 3, m_blk = (wid >> 2) & 127, z = wid >> 9;
  const float* A = (z == 0) ? q : (z == 1) ? k : v;
  const f16* W = WT + (size_t)z * DM * DM;
  f16* O = (z == 0) ? Qh : (z == 1) ? Kh : Vh;
  gemm_body<0>(A, nullptr, W, O, nullptr, m_blk * 128, n_blk * 128, z == 2);
}

__global__ __launch_bounds__(256, 2) void outp_k(const f16* __restrict__ ctx,
                                                 const f16* __restrict__ WoT,
                                                 float* __restrict__ out0) {
  const int bid = blockIdx.x;
  const int wid = (bid & 7) * 64 + (bid >> 3);
  const int n_blk = wid & 3, m_blk = wid >> 2;
  gemm_body<1>(nullptr, ctx, WoT, nullptr, out0, m_blk * 128, n_blk * 128, false);
}

// ---------------- attention ----------------
// Grid 512 (XCD-chunked), 4 waves, 256 q-rows/block (4 subtiles x 64 rows).
// Swapped QK^T: acc = logits[key][q], q = lane&15 (lq), keys = 16j + 4g + r.
// K/V staged once per kt for ALL 4 subtiles (4x staging-traffic cut).
// K-fragments read once per kt, reused across subtiles.
__global__ __launch_bounds__(256, 2) void attn_k(
    const f16* __restrict__ Qh, const f16* __restrict__ Kh, const f16* __restrict__ VTh,
    const float* __restrict__ mask, float* __restrict__ attnW, f16* __restrict__ ctx) {
  __shared__ __align__(16) f16 Ks[2][64 * 64];       // 16 KB
  __shared__ __align__(16) f16 Vt[2][64 * 64];       // 16 KB
  __shared__ __align__(16) f16 Ps[4][4][16 * 64];    // 32 KB [wave][subtile]
  __shared__ __align__(16) float Ms[SEQ];            // 4 KB
  const int tid = threadIdx.x;
  const int lane = tid & 63, wave = tid >> 6;
  const int lq = lane & 15, g = lane >> 4;
  const int bid = blockIdx.x;
  const int wid = (bid & 7) * 64 + (bid >> 3);       // bijective, 512 = 8*64
  const int qt4 = wid & 3, h = (wid >> 2) & 7, b = wid >> 5;
  const size_t bh = (size_t)b * NH + h;
  const char* Kbase = (const char*)(Kh + bh * SEQ * DH);
  const char* VTbase = (const char*)(VTh + bh * (size_t)DH * SEQ);
  const int qbase = qt4 * 256 + wave * 16;           // + st*64 + lq

  auto stageK = [&](int kt, int buf) {
    const char* KtileB = Kbase + (size_t)kt * 64 * DH * 2;
#pragma unroll
    for (int it = 0; it < 2; ++it) {
      const int o = (it * 256 + tid) * 16;
      const int key = o >> 7, slot = (o >> 4) & 7;
      async16((char*)&Ks[buf][0] + (it * 256 + wave * 64) * 16,
              KtileB + key * 128 + ((slot ^ (key & 7)) << 4));
    }
  };
  auto stageV = [&](int kt, int buf) {
    const char* VtileB = VTbase + (size_t)kt * 64 * 2;
#pragma unroll
    for (int it = 0; it < 2; ++it) {
      const int o = (it * 256 + tid) * 16;
      const int d = o >> 7, slot = (o >> 4) & 7;
      async16((char*)&Vt[buf][0] + (it * 256 + wave * 64) * 16,
              VtileB + (size_t)d * (SEQ * 2) + ((slot ^ (d & 7)) << 4));
    }
  };

  // bias preload
  {
    f32x4 mv = *(const f32x4*)(mask + (size_t)b * SEQ + tid * 4);
    f32x4 bv;
    bv[0] = (1.0f - mv[0]) * (-1e9f);
    bv[1] = (1.0f - mv[1]) * (-1e9f);
    bv[2] = (1.0f - mv[2]) * (-1e9f);
    bv[3] = (1.0f - mv[3]) * (-1e9f);
    *(f32x4*)&Ms[tid * 4] = bv;
  }

  // Q fragments for 4 subtiles (B-operand; row q = lq, k = g*8..)
  f16x8 aQ0[4], aQ1[4];
#pragma unroll
  for (int st = 0; st < 4; ++st) {
    const f16* qp = Qh + (bh * SEQ + qbase + st * 64 + lq) * DH + g * 8;
    aQ0[st] = *(const f16x8*)qp;
    aQ1[st] = *(const f16x8*)(qp + 32);
  }

  // ---- pass 1: denominators for all 4 subtiles ----
  float ssum[4] = {0.f, 0.f, 0.f, 0.f};
  stageK(0, 0);
  __syncthreads();
  for (int kt = 0; kt < 16; ++kt) {
    const int cur = kt & 1;
    if (kt < 15) stageK(kt + 1, cur ^ 1);
    f16x8 a0[4], a1[4];
#pragma unroll
    for (int j = 0; j < 4; ++j) {
      const int krow = j * 16 + lq;
      a0[j] = *(const f16x8*)((const char*)&Ks[cur][0] + krow * 128 + ((g ^ (krow & 7)) << 4));
      a1[j] = *(const f16x8*)((const char*)&Ks[cur][0] + krow * 128 + (((4 + g) ^ (krow & 7)) << 4));
    }
#pragma unroll
    for (int st = 0; st < 4; ++st) {
      f32x4 lg[4] = {};
#pragma unroll
      for (int j = 0; j < 4; ++j) {
        lg[j] = __builtin_amdgcn_mfma_f32_16x16x32_f16(a0[j], aQ0[st], lg[j], 0, 0, 0);
        lg[j] = __builtin_amdgcn_mfma_f32_16x16x32_f16(a1[j], aQ1[st], lg[j], 0, 0, 0);
      }
#pragma unroll
      for (int j = 0; j < 4; ++j) {
        f32x4 bias = *(const f32x4*)&Ms[kt * 64 + j * 16 + g * 4];
#pragma unroll
        for (int r = 0; r < 4; ++r) ssum[st] += __expf(lg[j][r] * 0.125f + bias[r]);
      }
    }
    __syncthreads();
  }

  float inv[4];
#pragma unroll
  for (int st = 0; st < 4; ++st) {
    float s = ssum[st];
    s += __shfl_xor(s, 16);
    s += __shfl_xor(s, 32);
    inv[st] = 1.0f / s;
  }

  // ---- pass 2 ----
  f32x4 ctxacc[4][4] = {};  // [subtile][j2]

  stageK(0, 0);
  stageV(0, 0);
  __syncthreads();
  for (int kt = 0; kt < 16; ++kt) {
    const int cur = kt & 1;
    if (kt < 15) {
      stageK(kt + 1, cur ^ 1);
      stageV(kt + 1, cur ^ 1);
    }
    f16x8 a0[4], a1[4];
#pragma unroll
    for (int j = 0; j < 4; ++j) {
      const int krow = j * 16 + lq;
      a0[j] = *(const f16x8*)((const char*)&Ks[cur][0] + krow * 128 + ((g ^ (krow & 7)) << 4));
      a1[j] = *(const f16x8*)((const char*)&Ks[cur][0] + krow * 128 + (((4 + g) ^ (krow & 7)) << 4));
    }
#pragma unroll
    for (int st = 0; st < 4; ++st) {
      f32x4 lg[4] = {};
#pragma unroll
      for (int j = 0; j < 4; ++j) {
        lg[j] = __builtin_amdgcn_mfma_f32_16x16x32_f16(a0[j], aQ0[st], lg[j], 0, 0, 0);
        lg[j] = __builtin_amdgcn_mfma_f32_16x16x32_f16(a1[j], aQ1[st], lg[j], 0, 0, 0);
      }
      float* awRow = attnW + ((bh * SEQ + qbase + st * 64 + lq) * SEQ) + kt * 64 + g * 4;
      char* psBase = (char*)&Ps[wave][st][0] + lq * 128;
#pragma unroll
      for (int j = 0; j < 4; ++j) {
        f32x4 bias = *(const f32x4*)&Ms[kt * 64 + j * 16 + g * 4];
        f32x4 w;
#pragma unroll
        for (int r = 0; r < 4; ++r) w[r] = __expf(lg[j][r] * 0.125f + bias[r]) * inv[st];
        *(f32x4*)(awRow + j * 16) = w;
        f16x4 pw;
        pw[0] = (f16)w[0]; pw[1] = (f16)w[1]; pw[2] = (f16)w[2]; pw[3] = (f16)w[3];
        const int slot = 2 * j + (g >> 1);
        *(f16x4*)(psBase + ((slot ^ (lq & 7)) << 4) + (g & 1) * 8) = pw;
      }
    }
    // PV: ctx[st][q][d] += P[st][q][k] @ V[k][d]  (bV shared across subtiles)
#pragma unroll
    for (int kk = 0; kk < 2; ++kk) {
      f16x8 aP[4];
#pragma unroll
      for (int st = 0; st < 4; ++st) {
        const int s = 4 * kk + g;
        aP[st] = *(const f16x8*)((const char*)&Ps[wave][st][0] + lq * 128 +
                                 ((s ^ (lq & 7)) << 4));
      }
#pragma unroll
      for (int j2 = 0; j2 < 4; ++j2) {
        const int drow = j2 * 16 + lq;
        f16x8 bV = *(const f16x8*)((const char*)&Vt[cur][0] + drow * 128 +
                                   (((4 * kk + g) ^ (drow & 7)) << 4));
#pragma unroll
        for (int st = 0; st < 4; ++st)
          ctxacc[st][j2] = __builtin_amdgcn_mfma_f32_16x16x32_f16(aP[st], bV, ctxacc[st][j2], 0, 0, 0);
      }
    }
    __syncthreads();
  }

  // ctx layout [b][s][h][d]: row = g*4+r (q-local), col = lq (d-local)
#pragma unroll
  for (int st = 0; st < 4; ++st)
#pragma unroll
    for (int j2 = 0; j2 < 4; ++j2)
#pragma unroll
      for (int r = 0; r < 4; ++r) {
        const int s = qbase + st * 64 + g * 4 + r;
        const int d = j2 * 16 + lq;
        ctx[(((size_t)b * SEQ + s) * NH + h) * DH + d] = (f16)ctxacc[st][j2][r];
      }
}

extern "C" void kernel_launch(void* const* d_in, const int* in_sizes, int n_in,
                              void* d_out, int out_size, void* d_ws, size_t ws_size,
                              hipStream_t stream) {
  const float* v = (const float*)d_in[0];
  const float* k = (const float*)d_in[1];
  const float* q = (const float*)d_in[2];
  const float* mask = (const float*)d_in[3];
  const float* Wq = (const float*)d_in[4];
  const float* Wk = (const float*)d_in[5];
  const float* Wv = (const float*)d_in[6];
  const float* Wo = (const float*)d_in[7];

  float* out0 = (float*)d_out;
  float* attnW = out0 + (size_t)BATCH * SEQ * DM;

  char* ws = (char*)d_ws;
  f16* WT = (f16*)ws;
  f16* Qh = (f16*)(ws + (size_t)4 * DM * DM * 2);
  f16* Kh = Qh + (size_t)BATCH * NH * SEQ * DH;
  f16* VTh = Kh + (size_t)BATCH * NH * SEQ * DH;  // [b][h][d][s]
  f16* ctx = VTh + (size_t)BATCH * NH * SEQ * DH;

  prep_wt_k<<<dim3(16, 16, 4), 256, 0, stream>>>(Wq, Wk, Wv, Wo, WT);
  proj_k<<<dim3(1536), 256, 0, stream>>>(q, k, v, WT, Qh, Kh, VTh);
  attn_k<<<dim3(512), 256, 0, stream>>>(Qh, Kh, VTh, mask, attnW, ctx);
  outp_k<<<dim3(512), 256, 0, stream>>>(ctx, WT + (size_t)3 * DM * DM, out0);
}